// Round 9
// baseline (771.178 us; speedup 1.0000x reference)
//
#include <hip/hip_runtime.h>
#include <math.h>

#define N_NODES 100000
#define N_EDGES 1600000
#define D 128
#define SCAN_CHUNK 1024
#define N_SCAN_BLOCKS 98   // ceil(100000/1024)
#define N_BUCKETS 98       // dst >> 10
#define EDGES_PER_PART 4096
#define N_PART_BLOCKS ((N_EDGES + EDGES_PER_PART - 1) / EDGES_PER_PART)  // 391

typedef short short8_t __attribute__((ext_vector_type(8)));
typedef short short4_t __attribute__((ext_vector_type(4)));
typedef short short2_t __attribute__((ext_vector_type(2)));
typedef float floatx4 __attribute__((ext_vector_type(4)));

__device__ __forceinline__ unsigned short f32_to_bf16_rne(float f) {
  unsigned u = __builtin_bit_cast(unsigned, f);
  unsigned r = u + 0x7fffu + ((u >> 16) & 1u);
  return (unsigned short)(r >> 16);
}
__device__ __forceinline__ float bf16_bits_to_f32(unsigned short h) {
  return __builtin_bit_cast(float, (unsigned)h << 16);
}

// ---------------- CSR build ----------------

__global__ __launch_bounds__(256) void k_count(const int* __restrict__ dst,
                                               int* __restrict__ counts) {
  int e = blockIdx.x * 256 + threadIdx.x;
  if (e < N_EDGES) atomicAdd(&counts[dst[e]], 1);
}

__global__ __launch_bounds__(256) void k_scan1(const int* __restrict__ counts,
                                               int* __restrict__ bsum) {
  __shared__ int red[256];
  int base = blockIdx.x * SCAN_CHUNK + threadIdx.x * 4;
  int s = 0;
#pragma unroll
  for (int j = 0; j < 4; j++) {
    int i = base + j;
    s += (i < N_NODES) ? counts[i] : 0;
  }
  red[threadIdx.x] = s;
  __syncthreads();
  for (int off = 128; off > 0; off >>= 1) {
    if (threadIdx.x < off) red[threadIdx.x] += red[threadIdx.x + off];
    __syncthreads();
  }
  if (threadIdx.x == 0) bsum[blockIdx.x] = red[0];
}

__global__ void k_scan2(const int* __restrict__ bsum, int* __restrict__ boff,
                        int* __restrict__ row_ptr, int nb) {
  if (threadIdx.x == 0) {
    int run = 0;
    for (int i = 0; i < nb; i++) { boff[i] = run; run += bsum[i]; }
    row_ptr[N_NODES] = run;   // == N_EDGES
  }
}

__global__ __launch_bounds__(256) void k_scan3(const int* __restrict__ counts,
                                               const int* __restrict__ boff,
                                               int* __restrict__ row_ptr,
                                               float* __restrict__ inv_deg) {
  __shared__ int sd[256];
  int base = blockIdx.x * SCAN_CHUNK + threadIdx.x * 4;
  int c[4];
  int s = 0;
#pragma unroll
  for (int j = 0; j < 4; j++) {
    int i = base + j;
    c[j] = (i < N_NODES) ? counts[i] : 0;
    s += c[j];
  }
  sd[threadIdx.x] = s;
  __syncthreads();
  for (int off = 1; off < 256; off <<= 1) {
    int add = (threadIdx.x >= off) ? sd[threadIdx.x - off] : 0;
    __syncthreads();
    sd[threadIdx.x] += add;
    __syncthreads();
  }
  int excl = (threadIdx.x ? sd[threadIdx.x - 1] : 0) + boff[blockIdx.x];
#pragma unroll
  for (int j = 0; j < 4; j++) {
    int i = base + j;
    if (i < N_NODES) {
      row_ptr[i] = excl;
      inv_deg[i] = 1.0f / fmaxf((float)c[j], 1.0f);
      excl += c[j];
    }
  }
}

__global__ void k_binit(const int* __restrict__ row_ptr,
                        int* __restrict__ bucket_cursor) {
  int t = threadIdx.x;
  if (t < N_BUCKETS) bucket_cursor[t] = row_ptr[t << 10];
}

// Partition pass: LDS-bin 4096 edges into 98 dst-range buckets; write (src,dst)
// pairs in contiguous per-(block,bucket) runs (coalesced; L2-combinable).
__global__ __launch_bounds__(1024) void k_part(const int* __restrict__ src,
                                               const int* __restrict__ dst,
                                               int* __restrict__ bucket_cursor,
                                               int2* __restrict__ ebuf) {
  __shared__ int2 eLDS[EDGES_PER_PART];
  __shared__ int hist[N_BUCKETS];
  __shared__ int lbase[N_BUCKETS];
  __shared__ int lcur[N_BUCKETS];
  __shared__ int gbase[N_BUCKETS];
  const int t = threadIdx.x;
  const int base = blockIdx.x * EDGES_PER_PART;
  const int count = min(EDGES_PER_PART, N_EDGES - base);
  if (t < N_BUCKETS) hist[t] = 0;
  __syncthreads();
  int s[4], d[4];
#pragma unroll
  for (int j = 0; j < 4; j++) {
    int local = j * 1024 + t;
    if (local < count) {
      s[j] = src[base + local];
      d[j] = dst[base + local];
      atomicAdd(&hist[d[j] >> 10], 1);
    } else {
      d[j] = -1;
    }
  }
  __syncthreads();
  if (t == 0) {
    int run = 0;
    for (int b = 0; b < N_BUCKETS; b++) { lbase[b] = run; run += hist[b]; }
  }
  __syncthreads();
  if (t < N_BUCKETS) {
    lcur[t] = lbase[t];
    gbase[t] = hist[t] ? atomicAdd(&bucket_cursor[t], hist[t]) : 0;
  }
  __syncthreads();
#pragma unroll
  for (int j = 0; j < 4; j++) {
    if (d[j] >= 0) {
      int p = atomicAdd(&lcur[d[j] >> 10], 1);
      eLDS[p] = make_int2(s[j], d[j]);
    }
  }
  __syncthreads();
#pragma unroll
  for (int j = 0; j < 4; j++) {
    int slot = j * 1024 + t;
    if (slot < count) {
      int2 e = eLDS[slot];
      int b = e.y >> 10;
      ebuf[gbase[b] + (slot - lbase[b])] = e;
    }
  }
}

// Local sort pass: one block per bucket; scatter src into ssrc positions via
// LDS per-node cursors. Writes land in the bucket's ~64KB window from a single
// CU/XCD -> L2 assembles full lines (kills the 16x write amplification).
__global__ __launch_bounds__(1024) void k_lsort(const int2* __restrict__ ebuf,
                                                const int* __restrict__ row_ptr,
                                                int* __restrict__ ssrc) {
  __shared__ int lcur[1024];
  const int b = blockIdx.x;
  const int t = threadIdx.x;
  const int node_base = b << 10;
  const int nb = min(1024, N_NODES - node_base);
  if (t < nb) lcur[t] = row_ptr[node_base + t];
  __syncthreads();
  const int rbeg = row_ptr[node_base];
  const int rend = row_ptr[node_base + nb];
  for (int i = rbeg + t; i < rend; i += 1024) {
    int2 e = ebuf[i];
    int p = atomicAdd(&lcur[e.y - node_base], 1);
    ssrc[p] = e.x;
  }
}

// ---------------- GIN aggregation: z = (1+eps)*h + mean_{j in N(i)} h_j ----------------
// v4: same per-lane float2 structure as the verified R4 kernel, but 8-edge
// groups (8 independent gathers in flight) with software-pipelined index
// loads: group k+1's indices issue BEFORE group k's gathers, so the in-order
// wave never has the index-load latency on the critical chain.
__global__ __launch_bounds__(256) void k_agg(const float* __restrict__ h,
                                             short* __restrict__ zh,
                                             short* __restrict__ zl,
                                             const int* __restrict__ row_ptr,
                                             const int* __restrict__ ssrc,
                                             const float* __restrict__ inv_deg,
                                             const float* __restrict__ eps,
                                             int layer) {
  const int t = threadIdx.x & 63;
  const int wv = threadIdx.x >> 6;
  const float* hp = h + 2 * t;
  const float ep1 = 1.0f + eps[layer];

  for (int node = blockIdx.x * 4 + wv; node < N_NODES; node += gridDim.x * 4) {
    const int beg = row_ptr[node];
    const int end = row_ptr[node + 1];
    const int cnt = end - beg;
    const int nfull = cnt & ~7;

    float axs[8], ays[8];
#pragma unroll
    for (int j = 0; j < 8; j++) { axs[j] = 0.f; ays[j] = 0.f; }

    int idx[8];
    if (nfull > 0) {
#pragma unroll
      for (int j = 0; j < 8; j++) idx[j] = ssrc[beg + j];
    }
    for (int g = 0; g < nfull; g += 8) {
      const int more = (g + 8 < nfull);  // wave-uniform
      int nidx[8];
      if (more) {
#pragma unroll
        for (int j = 0; j < 8; j++) nidx[j] = ssrc[beg + g + 8 + j];
      }
#pragma unroll
      for (int j = 0; j < 8; j++) {
        float2 v = *(const float2*)(hp + (size_t)idx[j] * D);
        axs[j] += v.x;
        ays[j] += v.y;
      }
      if (more) {
#pragma unroll
        for (int j = 0; j < 8; j++) idx[j] = nidx[j];
      }
    }
    for (int e = beg + nfull; e < end; ++e) {
      int i = ssrc[e];
      float2 v = *(const float2*)(hp + (size_t)i * D);
      axs[0] += v.x;
      ays[0] += v.y;
    }

    float sx = ((axs[0] + axs[1]) + (axs[2] + axs[3])) +
               ((axs[4] + axs[5]) + (axs[6] + axs[7]));
    float sy = ((ays[0] + ays[1]) + (ays[2] + ays[3])) +
               ((ays[4] + ays[5]) + (ays[6] + ays[7]));

    float2 hv = *(const float2*)(hp + (size_t)node * D);
    float id = inv_deg[node];
    float zx = ep1 * hv.x + sx * id;
    float zy = ep1 * hv.y + sy * id;
    unsigned short hx = f32_to_bf16_rne(zx);
    unsigned short hy = f32_to_bf16_rne(zy);
    unsigned short lx = f32_to_bf16_rne(zx - bf16_bits_to_f32(hx));
    unsigned short ly = f32_to_bf16_rne(zy - bf16_bits_to_f32(hy));
    short2_t hw, lw;
    hw[0] = (short)hx; hw[1] = (short)hy;
    lw[0] = (short)lx; lw[1] = (short)ly;
    *(short2_t*)&zh[(size_t)node * D + 2 * t] = hw;
    *(short2_t*)&zl[(size_t)node * D + 2 * t] = lw;
  }
}

// ---------------- W prep: split W[128][128] f32 -> WhT/WlT bf16 [col][k] ----------------
__global__ __launch_bounds__(256) void k_wprep(const float* __restrict__ W1,
                                               const float* __restrict__ W2,
                                               short* __restrict__ WT) {
  int mat = blockIdx.y;
  const float* Wsrc = (mat < 3) ? (W1 + (size_t)mat * D * D)
                                : (W2 + (size_t)(mat - 3) * D * D);
  int idx = blockIdx.x * 256 + threadIdx.x;  // 0..16383
  int k = idx >> 7;
  int c = idx & 127;
  float f = Wsrc[idx];
  unsigned short hi = f32_to_bf16_rne(f);
  float lo_f = f - bf16_bits_to_f32(hi);
  unsigned short lo = f32_to_bf16_rne(lo_f);
  short* base = WT + (size_t)mat * 2 * 16384;
  base[c * 128 + k] = (short)hi;
  base[16384 + c * 128 + k] = (short)lo;
}

// ---------------- split-bf16 MFMA GEMM, plane inputs, reg-prefetched K-loop ----------------
// A as bf16 hi/lo planes [row][k]; W pre-split [col][k]. 3 MFMA terms (hh,hl,lh).
// Block 128x128, 4 waves 2x2, wave tile 64x64 = 4x4 frags of 16x16x32.
#define LDS_STRIDE 40  // shorts per row (32 data + 8 pad) = 80B; frag reads 2-way (free)
__global__ __launch_bounds__(256, 2) void k_gemm(const short* __restrict__ Aph,
                                                 const short* __restrict__ Apl,
                                                 const short* __restrict__ WhT,
                                                 const short* __restrict__ WlT,
                                                 const float* __restrict__ bias,
                                                 float* __restrict__ Cf,
                                                 short* __restrict__ Cph,
                                                 short* __restrict__ Cpl,
                                                 int nrows, int plane_out) {
  __shared__ short Ah[128 * LDS_STRIDE];
  __shared__ short Al[128 * LDS_STRIDE];
  __shared__ short Wh[128 * LDS_STRIDE];
  __shared__ short Wl[128 * LDS_STRIDE];

  const int tid = threadIdx.x;
  const int row0 = blockIdx.x * 128;
  const int wave = tid >> 6;
  const int lane = tid & 63;
  const int wr = wave >> 1;
  const int wc = wave & 1;
  const int lr = lane & 15;
  const int koff = lane >> 4;

  floatx4 acc[4][4];
#pragma unroll
  for (int i = 0; i < 4; i++)
#pragma unroll
    for (int j = 0; j < 4; j++) acc[i][j] = (floatx4)(0.f);

  // staging: thread -> (row/col = tid>>1, k-half sa = 0 or 16 shorts)
  const int rs = tid >> 1;
  const int sa = (tid & 1) * 16;
  int arow = row0 + rs;
  if (arow >= nrows) arow = nrows - 1;
  const short* pAh = Aph + (size_t)arow * D;
  const short* pAl = Apl + (size_t)arow * D;
  const short* pWh = WhT + (size_t)rs * D;
  const short* pWl = WlT + (size_t)rs * D;

  short8_t rAh0, rAh1, rAl0, rAl1, rWh0, rWh1, rWl0, rWl1;
#define LOADREGS(K0)                                      \
  do {                                                    \
    rAh0 = *(const short8_t*)(pAh + (K0) + sa);           \
    rAh1 = *(const short8_t*)(pAh + (K0) + sa + 8);       \
    rAl0 = *(const short8_t*)(pAl + (K0) + sa);           \
    rAl1 = *(const short8_t*)(pAl + (K0) + sa + 8);       \
    rWh0 = *(const short8_t*)(pWh + (K0) + sa);           \
    rWh1 = *(const short8_t*)(pWh + (K0) + sa + 8);       \
    rWl0 = *(const short8_t*)(pWl + (K0) + sa);           \
    rWl1 = *(const short8_t*)(pWl + (K0) + sa + 8);       \
  } while (0)

  LOADREGS(0);
#pragma unroll
  for (int k0 = 0; k0 < 128; k0 += 32) {
    *(short8_t*)&Ah[rs * LDS_STRIDE + sa] = rAh0;
    *(short8_t*)&Ah[rs * LDS_STRIDE + sa + 8] = rAh1;
    *(short8_t*)&Al[rs * LDS_STRIDE + sa] = rAl0;
    *(short8_t*)&Al[rs * LDS_STRIDE + sa + 8] = rAl1;
    *(short8_t*)&Wh[rs * LDS_STRIDE + sa] = rWh0;
    *(short8_t*)&Wh[rs * LDS_STRIDE + sa + 8] = rWh1;
    *(short8_t*)&Wl[rs * LDS_STRIDE + sa] = rWl0;
    *(short8_t*)&Wl[rs * LDS_STRIDE + sa + 8] = rWl1;
    __syncthreads();
    if (k0 < 96) LOADREGS(k0 + 32);  // prefetch next tile under compute

    short8_t ah[4], al[4], wh[4], wl[4];
#pragma unroll
    for (int i = 0; i < 4; i++) {
      int r = wr * 64 + i * 16 + lr;
      ah[i] = *(const short8_t*)&Ah[r * LDS_STRIDE + koff * 8];
      al[i] = *(const short8_t*)&Al[r * LDS_STRIDE + koff * 8];
    }
#pragma unroll
    for (int j = 0; j < 4; j++) {
      int c = wc * 64 + j * 16 + lr;
      wh[j] = *(const short8_t*)&Wh[c * LDS_STRIDE + koff * 8];
      wl[j] = *(const short8_t*)&Wl[c * LDS_STRIDE + koff * 8];
    }
#pragma unroll
    for (int i = 0; i < 4; i++)
#pragma unroll
      for (int j = 0; j < 4; j++) {
        acc[i][j] = __builtin_amdgcn_mfma_f32_16x16x32_bf16(ah[i], wh[j], acc[i][j], 0, 0, 0);
        acc[i][j] = __builtin_amdgcn_mfma_f32_16x16x32_bf16(ah[i], wl[j], acc[i][j], 0, 0, 0);
        acc[i][j] = __builtin_amdgcn_mfma_f32_16x16x32_bf16(al[i], wh[j], acc[i][j], 0, 0, 0);
      }
    __syncthreads();
  }
#undef LOADREGS

  // ---- epilogue: bias + leaky_relu ----
  float bj[4];
#pragma unroll
  for (int j = 0; j < 4; j++) bj[j] = bias[wc * 64 + j * 16 + lr];
  if (plane_out) {
#pragma unroll
    for (int i = 0; i < 4; i++) {
#pragma unroll
      for (int r = 0; r < 4; r++) {
        int row = row0 + wr * 64 + i * 16 + koff * 4 + r;
        if (row < nrows) {
#pragma unroll
          for (int j = 0; j < 4; j++) {
            int col = wc * 64 + j * 16 + lr;
            float v = acc[i][j][r] + bj[j];
            v = v > 0.f ? v : 0.01f * v;
            unsigned short hv = f32_to_bf16_rne(v);
            unsigned short lv = f32_to_bf16_rne(v - bf16_bits_to_f32(hv));
            Cph[(size_t)row * D + col] = (short)hv;
            Cpl[(size_t)row * D + col] = (short)lv;
          }
        }
      }
    }
  } else {
#pragma unroll
    for (int i = 0; i < 4; i++) {
#pragma unroll
      for (int r = 0; r < 4; r++) {
        int row = row0 + wr * 64 + i * 16 + koff * 4 + r;
        if (row < nrows) {
#pragma unroll
          for (int j = 0; j < 4; j++) {
            int col = wc * 64 + j * 16 + lr;
            float v = acc[i][j][r] + bj[j];
            v = v > 0.f ? v : 0.01f * v;
            Cf[(size_t)row * D + col] = v;
          }
        }
      }
    }
  }
}

// ---------------- output head: n_out = h @ Wout[128,2] + bout ----------------
__global__ __launch_bounds__(256) void k_out(const float* __restrict__ h,
                                             const float* __restrict__ Wout,
                                             const float* __restrict__ bout,
                                             float* __restrict__ out) {
  int node = blockIdx.x * 4 + (threadIdx.x >> 6);
  int lane = threadIdx.x & 63;
  float2 hv = *(const float2*)(h + (size_t)node * D + lane * 2);
  float4 wv = *(const float4*)(Wout + lane * 4);
  float p0 = hv.x * wv.x + hv.y * wv.z;
  float p1 = hv.x * wv.y + hv.y * wv.w;
#pragma unroll
  for (int off = 32; off > 0; off >>= 1) {
    p0 += __shfl_down(p0, off, 64);
    p1 += __shfl_down(p1, off, 64);
  }
  if (lane == 0) {
    out[node * 2 + 0] = p0 + bout[0];
    out[node * 2 + 1] = p1 + bout[1];
  }
}

// ---------------- launch ----------------

extern "C" void kernel_launch(void* const* d_in, const int* in_sizes, int n_in,
                              void* d_out, int out_size, void* d_ws, size_t ws_size,
                              hipStream_t stream) {
  const float* x = (const float*)d_in[0];
  const int* src = (const int*)d_in[1];
  const int* dst = (const int*)d_in[2];
  const float* W1 = (const float*)d_in[3];
  const float* b1 = (const float*)d_in[4];
  const float* W2 = (const float*)d_in[5];
  const float* b2 = (const float*)d_in[6];
  const float* eps = (const float*)d_in[7];
  const float* Wout = (const float*)d_in[8];
  const float* bout = (const float*)d_in[9];
  float* out = (float*)d_out;
  float* n_embed = out + (size_t)2 * N_NODES;  // f32 h lives here between kernels

  char* ws = (char*)d_ws;
  size_t off = 0;
  auto alloc = [&](size_t bytes) -> char* {
    char* p = ws + off;
    off += (bytes + 511) & ~(size_t)511;
    return p;
  };
  short* zh = (short*)alloc(sizeof(short) * (size_t)N_NODES * D);  // 25.6 MB
  short* zl = (short*)alloc(sizeof(short) * (size_t)N_NODES * D);  // 25.6 MB
  int* ssrc = (int*)alloc(sizeof(int) * N_EDGES);                  // 6.4 MB
  int* counts = (int*)alloc(sizeof(int) * N_NODES);
  int* row_ptr = (int*)alloc(sizeof(int) * (N_NODES + 1));
  float* inv_deg = (float*)alloc(sizeof(float) * N_NODES);
  int* bsum = (int*)alloc(sizeof(int) * 128);
  int* boff = (int*)alloc(sizeof(int) * 128);
  int* bucket_cursor = (int*)alloc(sizeof(int) * 128);
  short* WT = (short*)alloc(sizeof(short) * 6 * 2 * 16384);        // 768 KB
  // ebuf (12.8 MB) aliases zh: dead before the first k_agg writes zh.
  int2* ebuf = (int2*)zh;

  // CSR build: count -> scan -> partition -> bucket-local sort
  hipMemsetAsync(counts, 0, sizeof(int) * N_NODES, stream);
  k_count<<<N_EDGES / 256, 256, 0, stream>>>(dst, counts);
  k_scan1<<<N_SCAN_BLOCKS, 256, 0, stream>>>(counts, bsum);
  k_scan2<<<1, 64, 0, stream>>>(bsum, boff, row_ptr, N_SCAN_BLOCKS);
  k_scan3<<<N_SCAN_BLOCKS, 256, 0, stream>>>(counts, boff, row_ptr, inv_deg);
  k_binit<<<1, 128, 0, stream>>>(row_ptr, bucket_cursor);
  k_part<<<N_PART_BLOCKS, 1024, 0, stream>>>(src, dst, bucket_cursor, ebuf);
  k_lsort<<<N_BUCKETS, 1024, 0, stream>>>(ebuf, row_ptr, ssrc);

  // W split/transpose (all 6 matrices)
  k_wprep<<<dim3(64, 6), 256, 0, stream>>>(W1, W2, WT);

  const int gemm_grid = (N_NODES + 127) / 128;  // 782
  // Per layer: agg(h -> planes); gemm1(planes -> planes, in-place); gemm2(planes -> h f32)
  for (int l = 0; l < 3; l++) {
    const float* hin = (l == 0) ? x : n_embed;
    const short* w1h = WT + (size_t)l * 2 * 16384;
    const short* w1l = w1h + 16384;
    const short* w2h = WT + (size_t)(3 + l) * 2 * 16384;
    const short* w2l = w2h + 16384;
    k_agg<<<2048, 256, 0, stream>>>(hin, zh, zl, row_ptr, ssrc, inv_deg, eps, l);
    k_gemm<<<gemm_grid, 256, 0, stream>>>(zh, zl, w1h, w1l, b1 + (size_t)l * D,
                                          (float*)nullptr, zh, zl, N_NODES, 1);
    k_gemm<<<gemm_grid, 256, 0, stream>>>(zh, zl, w2h, w2l, b2 + (size_t)l * D,
                                          n_embed, (short*)nullptr, (short*)nullptr,
                                          N_NODES, 0);
  }
  k_out<<<N_NODES / 4, 256, 0, stream>>>(n_embed, Wout, bout, out);
}